// Round 1
// baseline (519.895 us; speedup 1.0000x reference)
//
#include <hip/hip_runtime.h>
#include <math.h>

#define HID 64

// ---------------------------------------------------------------------------
// float atomic max via int/uint atomics (works for all non-NaN values when
// initialized to a very negative float):
//   val >= 0: bit patterns order like signed ints      -> atomicMax(int)
//   val <  0: bit patterns order REVERSED as unsigned  -> atomicMin(uint)
// Mixing is safe: any positive stored value has a small unsigned repr (wins
// atomicMin against negatives) and any negative repr is a negative signed int
// (loses atomicMax against positives).
// ---------------------------------------------------------------------------
__device__ __forceinline__ void atomicMaxFloat(float* addr, float val) {
    if (val >= 0.0f) {
        atomicMax((int*)addr, __float_as_int(val));
    } else {
        atomicMin((unsigned int*)addr, __float_as_uint(val));
    }
}

// v_dst[k] = sum_h W_dst[k][h] * att_dst[h]   (so a_dst = x @ v_dst, h_dst never materialized)
__global__ void vdst_kernel(const float* __restrict__ W_dst,
                            const float* __restrict__ att_dst,
                            float* __restrict__ vdst) {
    int k = threadIdx.x;  // 64 threads
    float acc = 0.0f;
#pragma unroll
    for (int h = 0; h < HID; ++h) acc = fmaf(W_dst[k * HID + h], att_dst[h], acc);
    vdst[k] = acc;
}

// seg_max = -1e30, denom = 0, accum = 0   (d_ws is poisoned 0xAA before every launch)
__global__ void init_kernel(float* __restrict__ segmax, float* __restrict__ denom,
                            float* __restrict__ accum, int N) {
    int stride = gridDim.x * blockDim.x;
    int i0 = blockIdx.x * blockDim.x + threadIdx.x;
    for (int i = i0; i < N; i += stride) {
        segmax[i] = -1e30f;
        denom[i] = 0.0f;
    }
    long long total = (long long)N * HID;
    for (long long i = i0; i < total; i += stride) accum[i] = 0.0f;
}

// h_src = x @ W_src ; a_src = h_src @ att_src ; a_dst = x @ vdst
// block = 256 threads = 4 waves, one wave per node, lane = output feature.
__global__ void proj_kernel(const float* __restrict__ x,
                            const float* __restrict__ W_src,
                            const float* __restrict__ att_src,
                            const float* __restrict__ vdst,
                            float* __restrict__ h_src,
                            float* __restrict__ a_src,
                            float* __restrict__ a_dst, int N) {
    __shared__ float Ws[HID * HID];
    __shared__ float attS[HID];
    __shared__ float vd[HID];
    __shared__ float xs[256];

    for (int i = threadIdx.x; i < HID * HID; i += 256) Ws[i] = W_src[i];
    if (threadIdx.x < HID) {
        attS[threadIdx.x] = att_src[threadIdx.x];
        vd[threadIdx.x] = vdst[threadIdx.x];
    }
    __syncthreads();

    const int wave = threadIdx.x >> 6;
    const int lane = threadIdx.x & 63;

    for (int base = blockIdx.x * 4; base < N; base += gridDim.x * 4) {
        __syncthreads();  // protect xs reuse across iterations
        long long gi = (long long)base * HID + threadIdx.x;
        xs[threadIdx.x] = (gi < (long long)N * HID) ? x[gi] : 0.0f;
        __syncthreads();

        int n = base + wave;
        if (n < N) {
            float acc = 0.0f;
#pragma unroll
            for (int k = 0; k < HID; ++k)
                acc = fmaf(xs[wave * HID + k], Ws[k * HID + lane], acc);
            h_src[(long long)n * HID + lane] = acc;

            // wave-reduce (width 64) two dot products
            float p = acc * attS[lane];
            float q = xs[wave * HID + lane] * vd[lane];
#pragma unroll
            for (int off = 32; off > 0; off >>= 1) {
                p += __shfl_down(p, off, 64);
                q += __shfl_down(q, off, 64);
            }
            if (lane == 0) {
                a_src[n] = p;
                a_dst[n] = q;
            }
        }
    }
}

// Per-edge logit e = LeakyReLU(a_src[src] + a_dst[tgt]); segment atomic max.
__global__ void edge_logit_kernel(const int* __restrict__ src, const int* __restrict__ tgt,
                                  const float* __restrict__ a_src,
                                  const float* __restrict__ a_dst,
                                  float* __restrict__ ebuf, float* __restrict__ segmax, int E) {
    int stride = gridDim.x * blockDim.x;
    for (int e = blockIdx.x * blockDim.x + threadIdx.x; e < E; e += stride) {
        int s = src[e], t = tgt[e];
        float v = a_src[s] + a_dst[t];
        v = (v > 0.0f) ? v : 0.2f * v;
        ebuf[e] = v;
        atomicMaxFloat(&segmax[t], v);
    }
}

// One wave per edge: w = exp(e - segmax[tgt]); denom[tgt] += w;
// accum[tgt][h] += w * h_src[src][h].  (Normalization deferred to out_kernel:
// sum(w*h)/(sum(w)+eps) == segment_sum(alpha*h) exactly.)
__global__ void aggregate_kernel(const int* __restrict__ src, const int* __restrict__ tgt,
                                 const float* __restrict__ ebuf,
                                 const float* __restrict__ segmax,
                                 const float* __restrict__ h_src,
                                 float* __restrict__ denom, float* __restrict__ accum, int E) {
    const int lane = threadIdx.x & 63;
    const int wid = (blockIdx.x * blockDim.x + threadIdx.x) >> 6;
    const int nwaves = (gridDim.x * blockDim.x) >> 6;
    for (int e = wid; e < E; e += nwaves) {
        int s = src[e], t = tgt[e];
        float w = __expf(ebuf[e] - segmax[t]);  // wave-uniform (broadcast loads)
        if (lane == 0) atomicAdd(&denom[t], w);
        float msg = w * h_src[(long long)s * HID + lane];
        atomicAdd(&accum[(long long)t * HID + lane], msg);
    }
}

// out = relu((accum/(denom+1e-16) + bias) @ W_lin + b_lin)
__global__ void out_kernel(const float* __restrict__ accum, const float* __restrict__ denom,
                           const float* __restrict__ bias,
                           const float* __restrict__ W_lin, const float* __restrict__ b_lin,
                           float* __restrict__ out, int N) {
    __shared__ float Wl[HID * HID];
    __shared__ float bs[HID];
    __shared__ float bl[HID];
    __shared__ float rs[256];

    for (int i = threadIdx.x; i < HID * HID; i += 256) Wl[i] = W_lin[i];
    if (threadIdx.x < HID) {
        bs[threadIdx.x] = bias[threadIdx.x];
        bl[threadIdx.x] = b_lin[threadIdx.x];
    }
    __syncthreads();

    const int wave = threadIdx.x >> 6;
    const int lane = threadIdx.x & 63;

    for (int base = blockIdx.x * 4; base < N; base += gridDim.x * 4) {
        __syncthreads();
        int n_load = base + (threadIdx.x >> 6);
        float r = 0.0f;
        if (n_load < N) {
            float d = denom[n_load];
            r = accum[(long long)n_load * HID + lane] / (d + 1e-16f) + bs[lane];
        }
        rs[threadIdx.x] = r;
        __syncthreads();

        int n = base + wave;
        if (n < N) {
            float acc = bl[lane];
#pragma unroll
            for (int k = 0; k < HID; ++k)
                acc = fmaf(rs[wave * HID + k], Wl[k * HID + lane], acc);
            out[(long long)n * HID + lane] = acc > 0.0f ? acc : 0.0f;
        }
    }
}

extern "C" void kernel_launch(void* const* d_in, const int* in_sizes, int n_in,
                              void* d_out, int out_size, void* d_ws, size_t ws_size,
                              hipStream_t stream) {
    const float* x       = (const float*)d_in[0];
    const int*   edge    = (const int*)d_in[1];   // int32 per harness convention
    const float* W_src   = (const float*)d_in[2];
    const float* W_dst   = (const float*)d_in[3];
    const float* att_src = (const float*)d_in[4];
    const float* att_dst = (const float*)d_in[5];
    const float* bias    = (const float*)d_in[6];
    const float* W_lin   = (const float*)d_in[7];
    const float* b_lin   = (const float*)d_in[8];
    float* out = (float*)d_out;

    const int N = in_sizes[0] / HID;  // 100000
    const int E = in_sizes[1] / 2;    // 1000000
    const int* src = edge;
    const int* tgt = edge + E;

    // workspace layout (floats)
    float* h_src  = (float*)d_ws;                    // N*64
    float* a_src  = h_src + (size_t)N * HID;         // N
    float* a_dst  = a_src + N;                       // N
    float* segmax = a_dst + N;                       // N
    float* denom  = segmax + N;                      // N
    float* accum  = denom + N;                       // N*64
    float* ebuf   = accum + (size_t)N * HID;         // E
    float* vdst   = ebuf + E;                        // 64

    vdst_kernel<<<1, 64, 0, stream>>>(W_dst, att_dst, vdst);
    init_kernel<<<2048, 256, 0, stream>>>(segmax, denom, accum, N);
    proj_kernel<<<2048, 256, 0, stream>>>(x, W_src, att_src, vdst, h_src, a_src, a_dst, N);
    edge_logit_kernel<<<1024, 256, 0, stream>>>(src, tgt, a_src, a_dst, ebuf, segmax, E);
    aggregate_kernel<<<2048, 256, 0, stream>>>(src, tgt, ebuf, segmax, h_src, denom, accum, E);
    out_kernel<<<2048, 256, 0, stream>>>(accum, denom, bias, W_lin, b_lin, out, N);
}

// Round 2
// 442.315 us; speedup vs baseline: 1.1754x; 1.1754x over previous
//
#include <hip/hip_runtime.h>
#include <math.h>

#define HID 64
#define CHUNK 1024   // elements scanned per block in the prefix-scan kernels

// v_dst[k] = sum_h W_dst[k][h] * att_dst[h]   (a_dst = x @ vdst; h_dst never materialized)
__global__ void vdst_kernel(const float* __restrict__ W_dst,
                            const float* __restrict__ att_dst,
                            float* __restrict__ vdst) {
    int k = threadIdx.x;  // 64 threads
    float acc = 0.0f;
#pragma unroll
    for (int h = 0; h < HID; ++h) acc = fmaf(W_dst[k * HID + h], att_dst[h], acc);
    vdst[k] = acc;
}

__global__ void zero_cnt_kernel(int* __restrict__ cnt, int N) {
    int stride = gridDim.x * blockDim.x;
    for (int i = blockIdx.x * blockDim.x + threadIdx.x; i < N; i += stride) cnt[i] = 0;
}

// h_src = x @ W_src ; a_src = h_src @ att_src ; a_dst = x @ vdst
__global__ void proj_kernel(const float* __restrict__ x,
                            const float* __restrict__ W_src,
                            const float* __restrict__ att_src,
                            const float* __restrict__ vdst,
                            float* __restrict__ h_src,
                            float* __restrict__ a_src,
                            float* __restrict__ a_dst, int N) {
    __shared__ float Ws[HID * HID];
    __shared__ float attS[HID];
    __shared__ float vd[HID];
    __shared__ float xs[256];

    for (int i = threadIdx.x; i < HID * HID; i += 256) Ws[i] = W_src[i];
    if (threadIdx.x < HID) {
        attS[threadIdx.x] = att_src[threadIdx.x];
        vd[threadIdx.x] = vdst[threadIdx.x];
    }
    __syncthreads();

    const int wave = threadIdx.x >> 6;
    const int lane = threadIdx.x & 63;

    for (int base = blockIdx.x * 4; base < N; base += gridDim.x * 4) {
        __syncthreads();  // protect xs reuse across iterations
        long long gi = (long long)base * HID + threadIdx.x;
        xs[threadIdx.x] = (gi < (long long)N * HID) ? x[gi] : 0.0f;
        __syncthreads();

        int n = base + wave;
        if (n < N) {
            float acc = 0.0f;
#pragma unroll
            for (int k = 0; k < HID; ++k)
                acc = fmaf(xs[wave * HID + k], Ws[k * HID + lane], acc);
            h_src[(long long)n * HID + lane] = acc;

            float p = acc * attS[lane];
            float q = xs[wave * HID + lane] * vd[lane];
#pragma unroll
            for (int off = 32; off > 0; off >>= 1) {
                p += __shfl_down(p, off, 64);
                q += __shfl_down(q, off, 64);
            }
            if (lane == 0) {
                a_src[n] = p;
                a_dst[n] = q;
            }
        }
    }
}

// cnt[t] = in-degree of node t
__global__ void hist_kernel(const int* __restrict__ tgt, int* __restrict__ cnt, int E) {
    int stride = gridDim.x * blockDim.x;
    for (int e = blockIdx.x * blockDim.x + threadIdx.x; e < E; e += stride)
        atomicAdd(&cnt[tgt[e]], 1);
}

// pass 1: per-block (CHUNK-elem) sums
__global__ void scan_reduce_kernel(const int* __restrict__ cnt, int* __restrict__ blocksum, int N) {
    __shared__ int sd[256];
    int b = blockIdx.x, t = threadIdx.x;
    int base = b * CHUNK + t * 4;
    int s = 0;
#pragma unroll
    for (int k = 0; k < 4; ++k) { int i = base + k; if (i < N) s += cnt[i]; }
    sd[t] = s;
    __syncthreads();
    for (int off = 128; off > 0; off >>= 1) {
        if (t < off) sd[t] += sd[t + off];
        __syncthreads();
    }
    if (t == 0) blocksum[b] = sd[0];
}

// pass 2: serial exclusive scan of ~98 block sums (negligible)
__global__ void scan_top_kernel(const int* __restrict__ blocksum, int* __restrict__ blockoff,
                                int nb, int* __restrict__ rowptr, int N) {
    if (blockIdx.x == 0 && threadIdx.x == 0) {
        int run = 0;
        for (int b = 0; b < nb; ++b) { blockoff[b] = run; run += blocksum[b]; }
        rowptr[N] = run;
    }
}

// pass 3: in-block exclusive scan + block offset -> rowptr, cursor
__global__ void scan_final_kernel(const int* __restrict__ cnt, const int* __restrict__ blockoff,
                                  int* __restrict__ rowptr, int* __restrict__ cursor, int N) {
    __shared__ int sd[256];
    int b = blockIdx.x, t = threadIdx.x;
    int base = b * CHUNK + t * 4;
    int c[4];
    int tot = 0;
#pragma unroll
    for (int k = 0; k < 4; ++k) { int i = base + k; c[k] = (i < N) ? cnt[i] : 0; tot += c[k]; }
    sd[t] = tot;
    __syncthreads();
    // Hillis-Steele inclusive scan over 256 thread totals
    for (int off = 1; off < 256; off <<= 1) {
        int x = (t >= off) ? sd[t - off] : 0;
        __syncthreads();
        sd[t] += x;
        __syncthreads();
    }
    int run = sd[t] - tot + blockoff[b];
#pragma unroll
    for (int k = 0; k < 4; ++k) {
        int i = base + k;
        if (i < N) { rowptr[i] = run; cursor[i] = run; run += c[k]; }
    }
}

// bucket each edge into its target's CSR slot; compute the LeakyReLU logit inline
__global__ void scatter_kernel(const int* __restrict__ src, const int* __restrict__ tgt,
                               const float* __restrict__ a_src, const float* __restrict__ a_dst,
                               int* __restrict__ cursor,
                               int* __restrict__ ss, float* __restrict__ slog, int E) {
    int stride = gridDim.x * blockDim.x;
    for (int e = blockIdx.x * blockDim.x + threadIdx.x; e < E; e += stride) {
        int s = src[e], t = tgt[e];
        float v = a_src[s] + a_dst[t];
        v = (v > 0.0f) ? v : 0.2f * v;
        int pos = atomicAdd(&cursor[t], 1);
        ss[pos] = s;
        slog[pos] = v;
    }
}

// One wave per node: softmax over its CSR bucket + weighted gather of h_src rows,
// then fused (r + bias) @ W_lin + b_lin -> ReLU via 64 in-wave shuffles. No atomics,
// no barriers in the node loop.
__global__ void gather_out_kernel(const int* __restrict__ rowptr,
                                  const int* __restrict__ ss, const float* __restrict__ slog,
                                  const float* __restrict__ h_src,
                                  const float* __restrict__ bias,
                                  const float* __restrict__ W_lin, const float* __restrict__ b_lin,
                                  float* __restrict__ out, int N) {
    __shared__ float Wl[HID * HID];
    __shared__ float bs[HID];
    __shared__ float bl[HID];

    for (int i = threadIdx.x; i < HID * HID; i += 256) Wl[i] = W_lin[i];
    if (threadIdx.x < HID) {
        bs[threadIdx.x] = bias[threadIdx.x];
        bl[threadIdx.x] = b_lin[threadIdx.x];
    }
    __syncthreads();

    const int lane = threadIdx.x & 63;
    const int wid = (blockIdx.x * blockDim.x + threadIdx.x) >> 6;
    const int nwaves = (gridDim.x * blockDim.x) >> 6;

    for (int n = wid; n < N; n += nwaves) {
        int beg = rowptr[n], end = rowptr[n + 1];

        // pass 1: segment max (lanes split the bucket, then butterfly all-reduce)
        float m = -1e30f;
        for (int j = beg + lane; j < end; j += 64) m = fmaxf(m, slog[j]);
#pragma unroll
        for (int off = 1; off < 64; off <<= 1) m = fmaxf(m, __shfl_xor(m, off, 64));

        // pass 2: exp-weight + gather-accumulate (lane = feature)
        float acc = 0.0f, dsum = 0.0f;
        for (int j = beg; j < end; ++j) {
            int s = ss[j];                       // wave-uniform broadcast load
            float w = __expf(slog[j] - m);       // wave-uniform
            dsum += w;
            acc = fmaf(w, h_src[(long long)s * HID + lane], acc);
        }

        float r = acc / (dsum + 1e-16f) + bs[lane];

        // fused output GEMM: out[l] = relu(b_lin[l] + sum_k r[k]*Wl[k][l])
        float o = bl[lane];
#pragma unroll
        for (int k = 0; k < HID; ++k) {
            float rk = __shfl(r, k, 64);
            o = fmaf(rk, Wl[k * HID + lane], o);
        }
        out[(long long)n * HID + lane] = (o > 0.0f) ? o : 0.0f;
    }
}

extern "C" void kernel_launch(void* const* d_in, const int* in_sizes, int n_in,
                              void* d_out, int out_size, void* d_ws, size_t ws_size,
                              hipStream_t stream) {
    const float* x       = (const float*)d_in[0];
    const int*   edge    = (const int*)d_in[1];
    const float* W_src   = (const float*)d_in[2];
    const float* W_dst   = (const float*)d_in[3];
    const float* att_src = (const float*)d_in[4];
    const float* att_dst = (const float*)d_in[5];
    const float* bias    = (const float*)d_in[6];
    const float* W_lin   = (const float*)d_in[7];
    const float* b_lin   = (const float*)d_in[8];
    float* out = (float*)d_out;

    const int N = in_sizes[0] / HID;  // 100000
    const int E = in_sizes[1] / 2;    // 1000000
    const int* src = edge;
    const int* tgt = edge + E;
    const int NB = (N + CHUNK - 1) / CHUNK;

    // workspace layout
    float* h_src   = (float*)d_ws;                   // N*HID
    float* a_src   = h_src + (size_t)N * HID;        // N
    float* a_dst   = a_src + N;                      // N
    float* vdst    = a_dst + N;                      // 64
    int*   cnt     = (int*)(vdst + 64);              // N
    int*   rowptr  = cnt + N;                        // N+1
    int*   cursor  = rowptr + N + 1;                 // N
    int*   blocksum= cursor + N;                     // NB
    int*   blockoff= blocksum + NB;                  // NB
    int*   ss      = blockoff + NB;                  // E
    float* slog    = (float*)(ss + E);               // E

    vdst_kernel<<<1, 64, 0, stream>>>(W_dst, att_dst, vdst);
    zero_cnt_kernel<<<512, 256, 0, stream>>>(cnt, N);
    proj_kernel<<<2048, 256, 0, stream>>>(x, W_src, att_src, vdst, h_src, a_src, a_dst, N);
    hist_kernel<<<1024, 256, 0, stream>>>(tgt, cnt, E);
    scan_reduce_kernel<<<NB, 256, 0, stream>>>(cnt, blocksum, N);
    scan_top_kernel<<<1, 64, 0, stream>>>(blocksum, blockoff, NB, rowptr, N);
    scan_final_kernel<<<NB, 256, 0, stream>>>(cnt, blockoff, rowptr, cursor, N);
    scatter_kernel<<<1024, 256, 0, stream>>>(src, tgt, a_src, a_dst, cursor, ss, slog, E);
    gather_out_kernel<<<2048, 256, 0, stream>>>(rowptr, ss, slog, h_src, bias, W_lin, b_lin, out, N);
}